// Round 1
// baseline (1665.559 us; speedup 1.0000x reference)
//
#include <hip/hip_runtime.h>
#include <math.h>

#define B_ 16
#define L_ 24
#define N_ 325
#define D_ 256
#define M_ (B_*L_*N_)            // 124800
#define EPS_ 1e-5f
#define INV_SCALE 0.17677669529663687f   // 1/sqrt(32); d_head=256/8=32 per reference

#define BM 64
#define BN 64
#define BK 16

// Y = A @ W + bias   (A: M_ x 256 row-major, W: 256 x 256 row-major f->o)
// plus per-output-channel sum / sum-of-squares accumulated via atomics.
__global__ __launch_bounds__(256, 4)
void gemm_bias_stats(const float* __restrict__ A, const float* __restrict__ W,
                     const float* __restrict__ bias, float* __restrict__ Y,
                     float* __restrict__ sumg, float* __restrict__ sumsqg) {
    __shared__ float As[BK][BM + 4];   // +4 pad: 16B-aligned rows, breaks bank conflicts
    __shared__ float Bs[BK][BN];
    __shared__ float csum[BN];
    __shared__ float csq[BN];
    const int tid  = threadIdx.x;
    const int tx   = tid & 15, ty = tid >> 4;     // 16x16 threads, 4x4 micro-tile
    const int row0 = blockIdx.y * BM;
    const int col0 = blockIdx.x * BN;
    const int ar   = tid >> 2;                    // A-tile row 0..63
    const int ak   = (tid & 3) << 2;              // A-tile k  0,4,8,12
    const int bkr  = tid >> 4;                    // B-tile k row 0..15
    const int bc   = (tid & 15) << 2;             // B-tile col

    if (tid < BN) { csum[tid] = 0.f; csq[tid] = 0.f; }

    float acc[4][4] = {{0.f}};

    for (int k0 = 0; k0 < D_; k0 += BK) {
        const float4 av = *(const float4*)(A + (size_t)(row0 + ar) * D_ + (k0 + ak));
        const float4 bv = *(const float4*)(W + (size_t)(k0 + bkr) * D_ + (col0 + bc));
        __syncthreads();
        As[ak + 0][ar] = av.x;
        As[ak + 1][ar] = av.y;
        As[ak + 2][ar] = av.z;
        As[ak + 3][ar] = av.w;
        *(float4*)(&Bs[bkr][bc]) = bv;
        __syncthreads();
#pragma unroll
        for (int kk = 0; kk < BK; ++kk) {
            const float4 a4 = *(const float4*)(&As[kk][ty << 2]);
            const float4 b4 = *(const float4*)(&Bs[kk][tx << 2]);
            const float aa[4] = {a4.x, a4.y, a4.z, a4.w};
            const float bb[4] = {b4.x, b4.y, b4.z, b4.w};
#pragma unroll
            for (int i = 0; i < 4; ++i)
#pragma unroll
                for (int j = 0; j < 4; ++j)
                    acc[i][j] = fmaf(aa[i], bb[j], acc[i][j]);
        }
    }

    float bcol[4];
#pragma unroll
    for (int j = 0; j < 4; ++j) bcol[j] = bias[col0 + (tx << 2) + j];

    float psum[4] = {0.f, 0.f, 0.f, 0.f};
    float psq[4]  = {0.f, 0.f, 0.f, 0.f};
#pragma unroll
    for (int i = 0; i < 4; ++i) {
        const int row = row0 + (ty << 2) + i;
        float v[4];
#pragma unroll
        for (int j = 0; j < 4; ++j) {
            v[j] = acc[i][j] + bcol[j];
            psum[j] += v[j];
            psq[j]  += v[j] * v[j];
        }
        float4 o4 = {v[0], v[1], v[2], v[3]};
        *(float4*)(Y + (size_t)row * D_ + col0 + (tx << 2)) = o4;
    }
#pragma unroll
    for (int j = 0; j < 4; ++j) {
        atomicAdd(&csum[(tx << 2) + j], psum[j]);
        atomicAdd(&csq[(tx << 2) + j],  psq[j]);
    }
    __syncthreads();
    if (tid < BN) {
        atomicAdd(&sumg[col0 + tid],   csum[tid]);
        atomicAdd(&sumsqg[col0 + tid], csq[tid]);
    }
}

// per-channel BN fold: ss[0..255] = gamma*rsqrt(var+eps), ss[256..511] = beta - mu*scale
__global__ void finalize_stats(const float* __restrict__ sum, const float* __restrict__ sumsq,
                               const float* __restrict__ gamma, const float* __restrict__ beta,
                               float* __restrict__ ss) {
    const int o = threadIdx.x;
    const float mu  = sum[o]   * (1.0f / (float)M_);
    const float var = sumsq[o] * (1.0f / (float)M_) - mu * mu;
    const float sc  = gamma[o] * rsqrtf(var + EPS_);
    ss[o]      = sc;
    ss[D_ + o] = beta[o] - mu * sc;
}

// One block per (b,n); 32 chunks x 8 head-dims = 256 threads.
// K,V staged in LDS with BN+ReLU applied on load; Q read per-thread (BN+ReLU in regs).
// outb may alias yq: all q reads complete before any output store (barrier-ordered,
// and each block's global read/write region is block-private).
__global__ __launch_bounds__(256, 2)
void attention_kernel(const float* __restrict__ yq, const float* __restrict__ yk,
                      const float* __restrict__ yv,
                      const float* __restrict__ ssq, const float* __restrict__ ssk,
                      const float* __restrict__ ssv,
                      float* __restrict__ outb) {
    __shared__ float ks[L_][D_];
    __shared__ float vs[L_][D_];
    const int blk = blockIdx.x;
    const int b   = blk / N_;
    const int n   = blk - b * N_;
    const int tid = threadIdx.x;

    for (int l = 0; l < L_; ++l) {
        const size_t g = ((size_t)(b * L_ + l) * N_ + n) * D_ + tid;
        ks[l][tid] = fmaxf(fmaf(yk[g], ssk[tid], ssk[D_ + tid]), 0.f);
        vs[l][tid] = fmaxf(fmaf(yv[g], ssv[tid], ssv[D_ + tid]), 0.f);
    }
    __syncthreads();

    const int c  = tid >> 3;          // chunk 0..31
    const int h  = tid & 7;           // owns 3 query rows: lq = 3h..3h+2
    const int d0 = c << 3;

    float outr[3][8];
#pragma unroll
    for (int r = 0; r < 3; ++r) {
        const int lq = h * 3 + r;
        const size_t gq = ((size_t)(b * L_ + lq) * N_ + n) * D_ + d0;
        const float4 q0 = *(const float4*)(yq + gq);
        const float4 q1 = *(const float4*)(yq + gq + 4);
        const float4 s0 = *(const float4*)(ssq + d0);
        const float4 s1 = *(const float4*)(ssq + d0 + 4);
        const float4 t0 = *(const float4*)(ssq + D_ + d0);
        const float4 t1 = *(const float4*)(ssq + D_ + d0 + 4);
        float qv[8];
        qv[0] = fmaxf(fmaf(q0.x, s0.x, t0.x), 0.f);
        qv[1] = fmaxf(fmaf(q0.y, s0.y, t0.y), 0.f);
        qv[2] = fmaxf(fmaf(q0.z, s0.z, t0.z), 0.f);
        qv[3] = fmaxf(fmaf(q0.w, s0.w, t0.w), 0.f);
        qv[4] = fmaxf(fmaf(q1.x, s1.x, t1.x), 0.f);
        qv[5] = fmaxf(fmaf(q1.y, s1.y, t1.y), 0.f);
        qv[6] = fmaxf(fmaf(q1.z, s1.z, t1.z), 0.f);
        qv[7] = fmaxf(fmaf(q1.w, s1.w, t1.w), 0.f);

        float scv[L_];
        float m = -1e30f;
#pragma unroll
        for (int lp = 0; lp < L_; ++lp) {
            float s = 0.f;
#pragma unroll
            for (int hh = 0; hh < 8; ++hh) s = fmaf(qv[hh], ks[lp][d0 + hh], s);
            s *= INV_SCALE;
            scv[lp] = s;
            m = fmaxf(m, s);
        }
        float sum = 0.f;
#pragma unroll
        for (int lp = 0; lp < L_; ++lp) { const float e = __expf(scv[lp] - m); scv[lp] = e; sum += e; }
        const float inv = 1.f / sum;
#pragma unroll
        for (int hh = 0; hh < 8; ++hh) {
            float o = 0.f;
#pragma unroll
            for (int lp = 0; lp < L_; ++lp) o = fmaf(scv[lp], vs[lp][d0 + hh], o);
            outr[r][hh] = o * inv;
        }
    }
    __syncthreads();               // everyone done reading ks/vs (and q from global)
#pragma unroll
    for (int r = 0; r < 3; ++r) {
        const int lq = h * 3 + r;
#pragma unroll
        for (int hh = 0; hh < 8; ++hh) ks[lq][d0 + hh] = outr[r][hh];  // reuse ks as staging
    }
    __syncthreads();
    for (int l = 0; l < L_; ++l) {
        const size_t g = ((size_t)(b * L_ + l) * N_ + n) * D_ + tid;
        outb[g] = ks[l][tid];
    }
}

__global__ __launch_bounds__(256, 4)
void bn_relu_out(const float* __restrict__ Y, const float* __restrict__ ss,
                 float* __restrict__ out) {
    const size_t i4 = ((size_t)blockIdx.x * 256 + threadIdx.x) << 2;
    const int d = (int)(i4 & (D_ - 1));
    const float4 y = *(const float4*)(Y + i4);
    const float4 s = *(const float4*)(ss + d);
    const float4 t = *(const float4*)(ss + D_ + d);
    float4 o;
    o.x = fmaxf(fmaf(y.x, s.x, t.x), 0.f);
    o.y = fmaxf(fmaf(y.y, s.y, t.y), 0.f);
    o.z = fmaxf(fmaf(y.z, s.z, t.z), 0.f);
    o.w = fmaxf(fmaf(y.w, s.w, t.w), 0.f);
    *(float4*)(out + i4) = o;
}

extern "C" void kernel_launch(void* const* d_in, const int* in_sizes, int n_in,
                              void* d_out, int out_size, void* d_ws, size_t ws_size,
                              hipStream_t stream) {
    const float* x   = (const float*)d_in[0];
    const float* stp = (const float*)d_in[1];
    const float* stf = (const float*)d_in[2];
    const float* Wq  = (const float*)d_in[3];
    const float* bq  = (const float*)d_in[4];
    const float* gq  = (const float*)d_in[5];
    const float* beq = (const float*)d_in[6];
    const float* Wk  = (const float*)d_in[7];
    const float* bk  = (const float*)d_in[8];
    const float* gk  = (const float*)d_in[9];
    const float* bek = (const float*)d_in[10];
    const float* Wv  = (const float*)d_in[11];
    const float* bv  = (const float*)d_in[12];
    const float* gv  = (const float*)d_in[13];
    const float* bev = (const float*)d_in[14];
    const float* Wo  = (const float*)d_in[15];
    const float* bo  = (const float*)d_in[16];
    const float* go  = (const float*)d_in[17];
    const float* beo = (const float*)d_in[18];

    float* ws = (float*)d_ws;
    const size_t nelem = (size_t)M_ * D_;           // 31,948,800
    float* yq    = ws;                              // q pre-BN; later attention output
    float* yk    = ws + nelem;                      // k pre-BN; later o-projection pre-BN
    float* stats = ws + 2 * nelem;                  // 4 x (sum[256], sumsq[256])
    float* ssq   = stats + 2048;                    // 4 x (scale[256], shift[256])
    float* ssk   = ssq + 512;
    float* ssv   = ssk + 512;
    float* sso   = ssv + 512;
    float* yv    = (float*)d_out;                   // v pre-BN rides in d_out (dead before final write)
    float* yo    = yk;                              // o-projection pre-BN reuses k buffer

    hipMemsetAsync(stats, 0, 2048 * sizeof(float), stream);

    dim3 gg(D_ / BN, M_ / BM);
    gemm_bias_stats<<<gg, 256, 0, stream>>>(stf, Wq, bq, yq, stats + 0,    stats + 256);
    gemm_bias_stats<<<gg, 256, 0, stream>>>(stp, Wk, bk, yk, stats + 512,  stats + 768);
    gemm_bias_stats<<<gg, 256, 0, stream>>>(x,   Wv, bv, yv, stats + 1024, stats + 1280);
    finalize_stats<<<1, 256, 0, stream>>>(stats + 0,    stats + 256,  gq, beq, ssq);
    finalize_stats<<<1, 256, 0, stream>>>(stats + 512,  stats + 768,  gk, bek, ssk);
    finalize_stats<<<1, 256, 0, stream>>>(stats + 1024, stats + 1280, gv, bev, ssv);
    attention_kernel<<<B_ * N_, 256, 0, stream>>>(yq, yk, yv, ssq, ssk, ssv, yq);
    gemm_bias_stats<<<gg, 256, 0, stream>>>(yq, Wo, bo, yo, stats + 1536, stats + 1792);
    finalize_stats<<<1, 256, 0, stream>>>(stats + 1536, stats + 1792, go, beo, sso);
    bn_relu_out<<<(M_ * D_) / 1024, 256, 0, stream>>>(yo, sso, (float*)d_out);
}

// Round 2
// 947.232 us; speedup vs baseline: 1.7583x; 1.7583x over previous
//
#include <hip/hip_runtime.h>
#include <math.h>
#include <stdint.h>

#define B_ 16
#define L_ 24
#define N_ 325
#define D_ 256
#define M_ (B_*L_*N_)            // 124800
#define EPS_ 1e-5f
#define INV_SCALE 0.17677669529663687f   // 1/sqrt(32)

typedef unsigned short ushort_t;
typedef __bf16 bf16_t;
typedef bf16_t bf16x8 __attribute__((ext_vector_type(8)));
typedef float f32x4 __attribute__((ext_vector_type(4)));

__device__ __forceinline__ ushort_t f2bf(float f) {
    union { float f; uint32_t u; } v; v.f = f;
    const uint32_t u = v.u;
    return (ushort_t)((u + 0x7FFFu + ((u >> 16) & 1u)) >> 16);   // RNE
}
__device__ __forceinline__ float bf2f(ushort_t h) {
    union { uint32_t u; float f; } v; v.u = ((uint32_t)h) << 16;
    return v.f;
}

#define GL2LDS(g, l) __builtin_amdgcn_global_load_lds( \
    (__attribute__((address_space(1))) void*)(g), \
    (__attribute__((address_space(3))) void*)(l), 16, 0, 0)

// ---------------------------------------------------------------------------
// Pack W (fp32 [k][n] 256x256) -> bf16 panels Wp[(k>>5)][n][k&31]
// grid: 256 blocks (k), 256 threads (n)
__global__ void pack_w(const float* __restrict__ W, ushort_t* __restrict__ Wp) {
    const int k = blockIdx.x, n = threadIdx.x;
    Wp[(size_t)(k >> 5) * (256 * 32) + (size_t)n * 32 + (k & 31)] = f2bf(W[(size_t)k * 256 + n]);
}

// Pack 3 activation matrices (fp32 M x 256) -> bf16 panels Ap[(k>>5)][m][k&31]
// One row per wave per iter, 8 iters; grid = 3*M/32 = 11700 blocks.
__global__ __launch_bounds__(256)
void pack_a3(const float* __restrict__ s0, const float* __restrict__ s1,
             const float* __restrict__ s2,
             ushort_t* __restrict__ d0, ushort_t* __restrict__ d1,
             ushort_t* __restrict__ d2) {
    const int tid = threadIdx.x;
    const int w = tid >> 6, l = tid & 63;
    const size_t mstride = (size_t)M_ * 32;
    const int base_row = blockIdx.x * 32 + w * 8;
#pragma unroll
    for (int it = 0; it < 8; ++it) {
        const int row = base_row + it;           // in [0, 3M)
        const float* src; ushort_t* dst; int r;
        if (row < M_)          { src = s0; dst = d0; r = row; }
        else if (row < 2 * M_) { src = s1; dst = d1; r = row - M_; }
        else                   { src = s2; dst = d2; r = row - 2 * M_; }
        const float4 v = *(const float4*)(src + (size_t)r * 256 + l * 4);
        ushort4 o; o.x = f2bf(v.x); o.y = f2bf(v.y); o.z = f2bf(v.z); o.w = f2bf(v.w);
        *(ushort4*)(dst + (size_t)(l >> 3) * mstride + (size_t)r * 32 + (l & 7) * 4) = o;
    }
}

// ---------------------------------------------------------------------------
// C = A @ W + bias, A: M x 256 bf16 (K-panel packed), W: 256 x 256 bf16 (K-panel packed)
// Y: M x 256 bf16 row-major. Per-col sum/sumsq (fp32, from pre-rounding values) via atomics.
// 128x128 tile, BK=32, 4 waves in 2x2, 16x16x32 MFMA, m97 structure.
__global__ __launch_bounds__(256)
void gemm_mfma(const ushort_t* __restrict__ Ap, const ushort_t* __restrict__ Wp,
               const float* __restrict__ bias, ushort_t* __restrict__ Y,
               float* __restrict__ sumg, float* __restrict__ sumsqg) {
    __shared__ ushort_t smem[16384];       // staging: As[128][32] + Bs[128][32]; reuse as Cs[128][128]
    __shared__ float csum[128], csq[128];
    ushort_t* As = smem;
    ushort_t* Bs = smem + 4096;

    const int tid  = threadIdx.x;
    const int w    = tid >> 6, lane = tid & 63;
    const int quad = lane >> 4, r = lane & 15;
    const int wm   = w & 1, wn = w >> 1;
    const int m0   = blockIdx.y * 128, n0 = blockIdx.x * 128;

    if (tid < 128) { csum[tid] = 0.f; csq[tid] = 0.f; }

    f32x4 acc[4][4];
#pragma unroll
    for (int i = 0; i < 4; ++i)
#pragma unroll
        for (int j = 0; j < 4; ++j) acc[i][j] = (f32x4){0.f, 0.f, 0.f, 0.f};

    const int arow = w * 32 + (lane >> 2);      // staging row (+ i*16)
    const int acol = (lane & 3) * 8;            // staging k-offset (ushorts)
    const size_t mstride = (size_t)M_ * 32;

    for (int k0 = 0; k0 < D_; k0 += 32) {
        const size_t panA = (size_t)(k0 >> 5) * mstride;
        const size_t panB = (size_t)(k0 >> 5) * (256 * 32);
        __syncthreads();                         // prior iter's ds_reads done
#pragma unroll
        for (int i = 0; i < 2; ++i) {
            GL2LDS(Ap + panA + (size_t)(m0 + arow + i * 16) * 32 + acol,
                   As + w * 1024 + i * 512);
            GL2LDS(Wp + panB + (size_t)(n0 + arow + i * 16) * 32 + acol,
                   Bs + w * 1024 + i * 512);
        }
        __syncthreads();                         // staging complete
        bf16x8 a[4], b[4];
#pragma unroll
        for (int i = 0; i < 4; ++i) a[i] = *(const bf16x8*)(As + (wm * 64 + i * 16 + r) * 32 + quad * 8);
#pragma unroll
        for (int j = 0; j < 4; ++j) b[j] = *(const bf16x8*)(Bs + (wn * 64 + j * 16 + r) * 32 + quad * 8);
#pragma unroll
        for (int i = 0; i < 4; ++i)
#pragma unroll
            for (int j = 0; j < 4; ++j)
                acc[i][j] = __builtin_amdgcn_mfma_f32_16x16x32_bf16(a[i], b[j], acc[i][j], 0, 0, 0);
    }

    __syncthreads();                             // all ds_reads done; smem -> Cs
    ushort_t* Cs = smem;                         // [128][128] bf16
    float bcol[4], psum[4] = {0, 0, 0, 0}, psq[4] = {0, 0, 0, 0};
#pragma unroll
    for (int j = 0; j < 4; ++j) bcol[j] = bias[n0 + wn * 64 + j * 16 + r];
#pragma unroll
    for (int i = 0; i < 4; ++i)
#pragma unroll
        for (int reg = 0; reg < 4; ++reg) {
            const int row_l = wm * 64 + i * 16 + quad * 4 + reg;
#pragma unroll
            for (int j = 0; j < 4; ++j) {
                const float val = acc[i][j][reg] + bcol[j];
                psum[j] += val; psq[j] += val * val;
                Cs[row_l * 128 + wn * 64 + j * 16 + r] = f2bf(val);
            }
        }
#pragma unroll
    for (int j = 0; j < 4; ++j) {
        atomicAdd(&csum[wn * 64 + j * 16 + r], psum[j]);
        atomicAdd(&csq[wn * 64 + j * 16 + r], psq[j]);
    }
    __syncthreads();
    const int cg = tid & 15, rr = tid >> 4;
#pragma unroll
    for (int it = 0; it < 8; ++it) {
        const int row = it * 16 + rr;
        const uint4 vv = *(const uint4*)(Cs + row * 128 + cg * 8);
        *(uint4*)(Y + (size_t)(m0 + row) * 256 + n0 + cg * 8) = vv;
    }
    if (tid < 128) {
        atomicAdd(&sumg[n0 + tid],   csum[tid]);
        atomicAdd(&sumsqg[n0 + tid], csq[tid]);
    }
}

// ---------------------------------------------------------------------------
__global__ void finalize_stats(const float* __restrict__ sum, const float* __restrict__ sumsq,
                               const float* __restrict__ gamma, const float* __restrict__ beta,
                               float* __restrict__ ss) {
    const int o = threadIdx.x;
    const float mu  = sum[o]   * (1.0f / (float)M_);
    const float var = sumsq[o] * (1.0f / (float)M_) - mu * mu;
    const float sc  = gamma[o] * rsqrtf(var + EPS_);
    ss[o]      = sc;
    ss[D_ + o] = beta[o] - mu * sc;
}

// ---------------------------------------------------------------------------
// One block per (b,n). Inputs: bf16 pre-BN Y matrices; BN+ReLU folded on load.
// Output written directly in packed-A bf16 layout for the O-projection GEMM.
__global__ __launch_bounds__(256, 2)
void attention_kernel(const ushort_t* __restrict__ yq, const ushort_t* __restrict__ yk,
                      const ushort_t* __restrict__ yv,
                      const float* __restrict__ ssq, const float* __restrict__ ssk,
                      const float* __restrict__ ssv,
                      ushort_t* __restrict__ Apo) {
    __shared__ float ks[L_][D_];
    __shared__ float vs[L_][D_];
    const int blk = blockIdx.x;
    const int b   = blk / N_;
    const int n   = blk - b * N_;
    const int tid = threadIdx.x;

    const float sck = ssk[tid], shk = ssk[D_ + tid];
    const float scv = ssv[tid], shv = ssv[D_ + tid];
    for (int l = 0; l < L_; ++l) {
        const size_t g = ((size_t)(b * L_ + l) * N_ + n) * D_ + tid;
        ks[l][tid] = fmaxf(fmaf(bf2f(yk[g]), sck, shk), 0.f);
        vs[l][tid] = fmaxf(fmaf(bf2f(yv[g]), scv, shv), 0.f);
    }
    __syncthreads();

    const int c = tid >> 3, h = tid & 7, d0 = c << 3;
    float outr[3][8];
#pragma unroll
    for (int rIdx = 0; rIdx < 3; ++rIdx) {
        const int lq = h * 3 + rIdx;
        const size_t gq = ((size_t)(b * L_ + lq) * N_ + n) * D_ + d0;
        const ushort4 qa = *(const ushort4*)(yq + gq);
        const ushort4 qb = *(const ushort4*)(yq + gq + 4);
        const float4 s0 = *(const float4*)(ssq + d0);
        const float4 s1 = *(const float4*)(ssq + d0 + 4);
        const float4 t0 = *(const float4*)(ssq + D_ + d0);
        const float4 t1 = *(const float4*)(ssq + D_ + d0 + 4);
        float qv[8];
        qv[0] = fmaxf(fmaf(bf2f(qa.x), s0.x, t0.x), 0.f);
        qv[1] = fmaxf(fmaf(bf2f(qa.y), s0.y, t0.y), 0.f);
        qv[2] = fmaxf(fmaf(bf2f(qa.z), s0.z, t0.z), 0.f);
        qv[3] = fmaxf(fmaf(bf2f(qa.w), s0.w, t0.w), 0.f);
        qv[4] = fmaxf(fmaf(bf2f(qb.x), s1.x, t1.x), 0.f);
        qv[5] = fmaxf(fmaf(bf2f(qb.y), s1.y, t1.y), 0.f);
        qv[6] = fmaxf(fmaf(bf2f(qb.z), s1.z, t1.z), 0.f);
        qv[7] = fmaxf(fmaf(bf2f(qb.w), s1.w, t1.w), 0.f);

        float scvrow[L_];
        float m = -1e30f;
#pragma unroll
        for (int lp = 0; lp < L_; ++lp) {
            float s = 0.f;
#pragma unroll
            for (int hh = 0; hh < 8; ++hh) s = fmaf(qv[hh], ks[lp][d0 + hh], s);
            s *= INV_SCALE;
            scvrow[lp] = s;
            m = fmaxf(m, s);
        }
        float sum = 0.f;
#pragma unroll
        for (int lp = 0; lp < L_; ++lp) { const float e = __expf(scvrow[lp] - m); scvrow[lp] = e; sum += e; }
        const float inv = 1.f / sum;
#pragma unroll
        for (int hh = 0; hh < 8; ++hh) {
            float o = 0.f;
#pragma unroll
            for (int lp = 0; lp < L_; ++lp) o = fmaf(scvrow[lp], vs[lp][d0 + hh], o);
            outr[rIdx][hh] = o * inv;
        }
    }
    __syncthreads();
#pragma unroll
    for (int rIdx = 0; rIdx < 3; ++rIdx) {
        const int lq = h * 3 + rIdx;
#pragma unroll
        for (int hh = 0; hh < 8; ++hh) ks[lq][d0 + hh] = outr[rIdx][hh];
    }
    __syncthreads();
    const size_t mstride = (size_t)M_ * 32;
    for (int l = 0; l < L_; ++l) {
        const size_t m = (size_t)(b * L_ + l) * N_ + n;
        Apo[(size_t)(tid >> 5) * mstride + m * 32 + (tid & 31)] = f2bf(ks[l][tid]);
    }
}

// ---------------------------------------------------------------------------
__global__ __launch_bounds__(256)
void bn_relu_out(const ushort_t* __restrict__ Y, const float* __restrict__ ss,
                 float* __restrict__ out) {
    const size_t i4 = ((size_t)blockIdx.x * 256 + threadIdx.x) << 2;
    const int d = (int)(i4 & (D_ - 1));
    const ushort4 y = *(const ushort4*)(Y + i4);
    const float4 s = *(const float4*)(ss + d);
    const float4 t = *(const float4*)(ss + D_ + d);
    float4 o;
    o.x = fmaxf(fmaf(bf2f(y.x), s.x, t.x), 0.f);
    o.y = fmaxf(fmaf(bf2f(y.y), s.y, t.y), 0.f);
    o.z = fmaxf(fmaf(bf2f(y.z), s.z, t.z), 0.f);
    o.w = fmaxf(fmaf(bf2f(y.w), s.w, t.w), 0.f);
    *(float4*)(out + i4) = o;
}

// ---------------------------------------------------------------------------
extern "C" void kernel_launch(void* const* d_in, const int* in_sizes, int n_in,
                              void* d_out, int out_size, void* d_ws, size_t ws_size,
                              hipStream_t stream) {
    const float* x   = (const float*)d_in[0];
    const float* stp = (const float*)d_in[1];
    const float* stf = (const float*)d_in[2];
    const float* Wq  = (const float*)d_in[3];
    const float* bq  = (const float*)d_in[4];
    const float* gq  = (const float*)d_in[5];
    const float* beq = (const float*)d_in[6];
    const float* Wk  = (const float*)d_in[7];
    const float* bk  = (const float*)d_in[8];
    const float* gk  = (const float*)d_in[9];
    const float* bek = (const float*)d_in[10];
    const float* Wv  = (const float*)d_in[11];
    const float* bv  = (const float*)d_in[12];
    const float* gv  = (const float*)d_in[13];
    const float* bev = (const float*)d_in[14];
    const float* Wo  = (const float*)d_in[15];
    const float* bo  = (const float*)d_in[16];
    const float* go  = (const float*)d_in[17];
    const float* beo = (const float*)d_in[18];

    const size_t S = (size_t)M_ * D_;            // elements per plane
    ushort_t* planeA = (ushort_t*)d_ws;          // Apq -> Yk
    ushort_t* planeB = planeA + S;               // Apk -> Apo (attn out, packed)
    ushort_t* planeC = planeB + S;               // Apv -> Yo
    ushort_t* planeD = planeC + S;               // Yq
    float* tail  = (float*)(planeD + S);         // == ws + 2*S floats (round-1 footprint)
    float* stats = tail;                         // 2048 floats
    float* ssq   = tail + 2048;
    float* ssk   = ssq + 512;
    float* ssv   = ssk + 512;
    float* sso   = ssv + 512;

    ushort_t* Yv  = (ushort_t*)d_out;            // lower half of d_out (bf16)
    ushort_t* WpQ = ((ushort_t*)d_out) + S;      // packed weights in d_out's upper half
    ushort_t* WpK = WpQ + 256 * 256;
    ushort_t* WpV = WpK + 256 * 256;
    ushort_t* WpO = WpV + 256 * 256;
    ushort_t* Yo  = planeC;

    hipMemsetAsync(stats, 0, 2048 * sizeof(float), stream);
    pack_w<<<256, 256, 0, stream>>>(Wq, WpQ);
    pack_w<<<256, 256, 0, stream>>>(Wk, WpK);
    pack_w<<<256, 256, 0, stream>>>(Wv, WpV);
    pack_w<<<256, 256, 0, stream>>>(Wo, WpO);
    pack_a3<<<(3 * M_) / 32, 256, 0, stream>>>(stf, stp, x, planeA, planeB, planeC);

    dim3 gg(2, M_ / 128);
    gemm_mfma<<<gg, 256, 0, stream>>>(planeA, WpQ, bq, planeD, stats + 0,    stats + 256);
    gemm_mfma<<<gg, 256, 0, stream>>>(planeB, WpK, bk, planeA, stats + 512,  stats + 768);
    gemm_mfma<<<gg, 256, 0, stream>>>(planeC, WpV, bv, Yv,     stats + 1024, stats + 1280);
    finalize_stats<<<1, 256, 0, stream>>>(stats + 0,    stats + 256,  gq, beq, ssq);
    finalize_stats<<<1, 256, 0, stream>>>(stats + 512,  stats + 768,  gk, bek, ssk);
    finalize_stats<<<1, 256, 0, stream>>>(stats + 1024, stats + 1280, gv, bev, ssv);
    attention_kernel<<<B_ * N_, 256, 0, stream>>>(planeD, planeA, Yv, ssq, ssk, ssv, planeB);
    gemm_mfma<<<gg, 256, 0, stream>>>(planeB, WpO, bo, Yo, stats + 1536, stats + 1792);
    finalize_stats<<<1, 256, 0, stream>>>(stats + 1536, stats + 1792, go, beo, sso);
    bn_relu_out<<<(int)(S / 1024), 256, 0, stream>>>(Yo, sso, (float*)d_out);
}